// Round 14
// baseline (169.904 us; speedup 1.0000x reference)
//
#include <hip/hip_runtime.h>
#include <hip/hip_fp16.h>
#include <math.h>

#define NN 50000
#define FD 8
#define TD 12
#define HD 64
#define FT 96            // FD*TD halves per node
#define EE 1600000
#define NBUK 391         // ceil(NN/128) dst buckets of 128 nodes
#define TILE 16384
#define NT 98            // ceil(EE/TILE)
#define SORTCAP 5120     // LDS staging cap per bucket (mean 4096, sigma 64 -> +16s)

// ws offsets (4B units)
#define OFF_GHIST 0                      // int[NBUK]
#define OFF_BASE  512                    // int[NBUK+1]
#define OFF_CUR   1024                   // int[NBUK]
#define OFF_ROWST 2048                   // int[NN+1]
#define OFF_DINV  (2048 + NN + 16)       // float[NN]
#define OFF_FUSED (OFF_DINV + NN)        // float[1164]
#define OFF_XH    (OFF_FUSED + 1184)     // half[NN*FT] t-major = NN*48 units
#define OFF_BEDGE (OFF_XH + NN*48)       // int2[EE] = 2*EE units
// total ~= 5.7M units ~= 22.8 MB

__device__ inline void h8f(uint4 h, float* f) {
    const __half2* p = (const __half2*)&h;
#pragma unroll
    for (int i = 0; i < 4; ++i) {
        float2 v = __half22float2(p[i]);
        f[2 * i] = v.x; f[2 * i + 1] = v.y;
    }
}

__device__ inline uint4 f8h(const float* f) {
    uint4 o;
    __half2* p = (__half2*)&o;
#pragma unroll
    for (int i = 0; i < 4; ++i) p[i] = __floats2half2_rn(f[2 * i], f[2 * i + 1]);
    return o;
}

// also zeroes ghist (k_zero folded in)
__global__ void k_precompute(const float* __restrict__ conv_w,
                             const float* __restrict__ conv_b,
                             const float* __restrict__ lin_w,
                             const float* __restrict__ lin_b,
                             const float* __restrict__ attention,
                             float* __restrict__ fused,
                             int* __restrict__ ghist) {
    int tid = threadIdx.x;
    if (tid < NBUK) ghist[tid] = 0;
    // Wzz (0..511): f,h -> sum_k conv_w[f][k]    * lin_w[0][k][h]
    // Whh (512..1023):    sum_k conv_w[f][128+k] * lin_w[2][k][h]
    for (int idx = tid; idx < 1024; idx += blockDim.x) {
        int sel = idx >> 9;
        int f = (idx & 511) >> 6;
        int h = idx & 63;
        const float* cw = conv_w + f * 192 + (sel ? 128 : 0);
        const float* lw = lin_w + (sel ? 2 * 128 * 64 : 0) + h;
        float s = 0.f;
        for (int k = 0; k < 64; ++k) s += cw[k] * lw[k * 64];
        fused[idx] = s;
    }
    // bzz (1024..1087), bhh (1088..1151)
    for (int idx = tid; idx < 128; idx += blockDim.x) {
        int sel = idx >> 6;
        int h = idx & 63;
        const float* cb = conv_b + (sel ? 128 : 0);
        const float* lw = lin_w + (sel ? 2 * 128 * 64 : 0) + h;
        float s = lin_b[(sel ? 2 * 64 : 0) + h];
        for (int k = 0; k < 64; ++k) s += cb[k] * lw[k * 64];
        fused[1024 + idx] = s;
    }
    // probs (1152..1163): softmax(attention)
    if (tid == 0) {
        float m = attention[0];
        for (int t = 1; t < TD; ++t) m = fmaxf(m, attention[t]);
        float e[TD], sum = 0.f;
        for (int t = 0; t < TD; ++t) { e[t] = __expf(attention[t] - m); sum += e[t]; }
        for (int t = 0; t < TD; ++t) fused[1152 + t] = e[t] / sum;
    }
}

// x (f-major fp32) -> xh (t-major fp16): thread = (node, t), one uint4 out
__global__ void k_xhalf(const float* __restrict__ x, uint4* __restrict__ xh4) {
    unsigned i = blockIdx.x * 256u + threadIdx.x;
    if (i >= (unsigned)NN * 12u) return;
    unsigned n = i / 12u, t = i - n * 12u;
    const float* xp = x + (size_t)n * FT + t;
    float f[8];
#pragma unroll
    for (int k = 0; k < 8; ++k) f[k] = xp[k * 12];
    xh4[i] = f8h(f);
}

// LDS-aggregated bucket histogram: ~NBUK global atomics per tile (not per edge)
__global__ __launch_bounds__(1024) void k_hist(const int* __restrict__ ei,
                                               int* __restrict__ ghist) {
    __shared__ int h[NBUK];
    int tid = threadIdx.x;
    for (int i = tid; i < NBUK; i += 1024) h[i] = 0;
    __syncthreads();
    int base = blockIdx.x * TILE;
    for (int i = 0; i < TILE / 1024; ++i) {
        int e = base + i * 1024 + tid;
        if (e < EE) atomicAdd(&h[ei[EE + e] >> 7], 1);
    }
    __syncthreads();
    for (int i = tid; i < NBUK; i += 1024)
        if (h[i]) atomicAdd(&ghist[i], h[i]);
}

// exclusive scan of bucket counts -> bucket bases + append cursors
__global__ void k_scan(const int* __restrict__ ghist, int* __restrict__ bktbase,
                       int* __restrict__ cursor) {
    __shared__ int s[512];
    int tid = threadIdx.x;
    int v = (tid < NBUK) ? ghist[tid] : 0;
    s[tid] = v;
    __syncthreads();
    for (int off = 1; off < 512; off <<= 1) {
        int t = (tid >= off) ? s[tid - off] : 0;
        __syncthreads();
        s[tid] += t;
        __syncthreads();
    }
    int excl = s[tid] - v;
    if (tid < NBUK) { bktbase[tid] = excl; cursor[tid] = excl; }
    if (tid == NBUK - 1) bktbase[NBUK] = excl + v;   // == EE
}

// tile claims per-bucket ranges (one global atomic per (tile,bucket)), then
// writes packed edges grouped by bucket: (src | dst_local<<16, w)
__global__ __launch_bounds__(1024) void k_place(const int* __restrict__ ei,
                                                const float* __restrict__ w,
                                                int* __restrict__ cursor,
                                                int2* __restrict__ bedge) {
    __shared__ int h[NBUK], bbase[NBUK];
    int tid = threadIdx.x;
    for (int i = tid; i < NBUK; i += 1024) h[i] = 0;
    __syncthreads();
    int base = blockIdx.x * TILE;
    for (int i = 0; i < TILE / 1024; ++i) {
        int e = base + i * 1024 + tid;
        if (e < EE) atomicAdd(&h[ei[EE + e] >> 7], 1);
    }
    __syncthreads();
    for (int i = tid; i < NBUK; i += 1024) {
        int c = h[i];
        bbase[i] = c ? atomicAdd(&cursor[i], c) : 0;
        h[i] = 0;
    }
    __syncthreads();
    for (int i = 0; i < TILE / 1024; ++i) {
        int e = base + i * 1024 + tid;
        if (e < EE) {
            int dst = ei[EE + e];
            int bk = dst >> 7;
            int rank = atomicAdd(&h[bk], 1);   // LDS rank within (tile,bucket)
            bedge[bbase[bk] + rank] =
                make_int2(ei[e] | ((dst & 127) << 16), __float_as_int(w[e]));
        }
    }
}

// per-bucket LDS counting sort by dst-local; writes back IN PLACE (block-local
// dense region), emits rowstart + dinv as by-products. Zero global atomics.
__global__ __launch_bounds__(512) void k_sort(const int* __restrict__ bktbase,
                                              int2* __restrict__ bedge,
                                              int* __restrict__ rowstart,
                                              float* __restrict__ dinv) {
    __shared__ int2 stage[SORTCAP];   // 40 KB
    __shared__ int cnt[128];
    __shared__ float wd[128];
    __shared__ int rowbase[128];
    int tid = threadIdx.x, b = blockIdx.x;
    int es = bktbase[b], ee = bktbase[b + 1];
    int count = ee - es;
    if (count > SORTCAP) count = SORTCAP;   // statistically unreachable
    if (tid < 128) { cnt[tid] = 0; wd[tid] = 0.f; }
    __syncthreads();
    for (int i = tid; i < count; i += 512) {
        int2 u = bedge[es + i];
        stage[i] = u;
        int dl = u.x >> 16;
        atomicAdd(&cnt[dl], 1);
        atomicAdd(&wd[dl], __int_as_float(u.y));
    }
    __syncthreads();
    // inclusive scan of cnt -> rowbase, then make exclusive
    if (tid < 128) rowbase[tid] = cnt[tid];
    __syncthreads();
    for (int off = 1; off < 128; off <<= 1) {
        int t = 0;
        if (tid >= off && tid < 128) t = rowbase[tid - off];
        __syncthreads();
        if (tid < 128) rowbase[tid] += t;
        __syncthreads();
    }
    int dbase = b << 7;
    if (tid < 128) {
        int excl = rowbase[tid] - cnt[tid];
        rowbase[tid] = excl;
        if (dbase + tid < NN) {
            rowstart[dbase + tid] = es + excl;
            dinv[dbase + tid] = rsqrtf(1.0f + wd[tid]);   // self-loop weight 1
        }
        cnt[tid] = 0;   // reuse as per-dst rank cursor
    }
    if (b == NBUK - 1 && tid == 0) rowstart[NN] = ee;
    __syncthreads();
    for (int i = tid; i < count; i += 512) {
        int2 u = stage[i];
        int dl = u.x >> 16;
        int pos = atomicAdd(&cnt[dl], 1);
        bedge[es + rowbase[dl] + pos] = make_int2(u.x & 0xFFFF, u.y);
    }
}

// FUSED gather + GRU + classifier.
// Block = 384 thr = 6 waves = 32 nodes.
// Phase G (no barriers): lane = (node, t-chunk), 12 lanes/node, 2-edge unroll;
//   result written to r_lds (2 LDS stores/lane).
// Phase N: lane = h (weights in registers); 6 waves split nodes 6/6/5/5/5/5;
//   rcp-based gates; rel -> rel_lds.
// Phase C: exactly one (node,t) item per thread, b128 dot over rel x cwT.
__global__ __launch_bounds__(384) void k_fused(const uint4* __restrict__ xh4,
                                               const float* __restrict__ dinv,
                                               const int* __restrict__ rowstart,
                                               const int2* __restrict__ edata,
                                               const float* __restrict__ fused,
                                               const float* __restrict__ cls_w,
                                               const float* __restrict__ cls_b,
                                               float* __restrict__ out) {
    __shared__ float r_lds[32 * 100];     // [node][t*8+f], stride 100
    __shared__ float rel_lds[32 * 68];    // [node][h], stride 68
    __shared__ float cwT_lds[12 * 68];    // cw transposed [t][h], stride 68
    __shared__ float cb_lds[12];
    __shared__ float probs_lds[12];
    int tid = threadIdx.x;
    int nbase = blockIdx.x * 32;

    // stage classifier weights (2 iters/thread)
    for (int id = tid; id < 768; id += 384) {
        int hh = id / 12, t = id - hh * 12;
        cwT_lds[t * 68 + hh] = cls_w[id];
    }
    if (tid < 12) { cb_lds[tid] = cls_b[tid]; probs_lds[tid] = fused[1152 + tid]; }

    // ---- Phase G: gather (independent lanes, no sync needed inside) ----
    int nl = tid / 12, c = tid - nl * 12;
    int n = nbase + nl;
    if (n < NN) {
        float dv = dinv[n];
        float a[8];
        h8f(xh4[(unsigned)n * 12u + c], a);
#pragma unroll
        for (int j = 0; j < 8; ++j) a[j] *= dv;      // self-loop dinv[n]*x[n]
        int rs = rowstart[n], re = rowstart[n + 1];
        int k = rs;
        for (; k + 1 < re; k += 2) {                 // 2 independent chains
            int2 pa = edata[k], pb = edata[k + 1];
            float ca = dinv[pa.x] * __int_as_float(pa.y);
            float cb2 = dinv[pb.x] * __int_as_float(pb.y);
            float va[8], vb[8];
            h8f(xh4[(unsigned)pa.x * 12u + c], va);
            h8f(xh4[(unsigned)pb.x * 12u + c], vb);
#pragma unroll
            for (int j = 0; j < 8; ++j) a[j] += ca * va[j] + cb2 * vb[j];
        }
        if (k < re) {
            int2 p = edata[k];
            float co = dinv[p.x] * __int_as_float(p.y);
            float v[8];
            h8f(xh4[(unsigned)p.x * 12u + c], v);
#pragma unroll
            for (int j = 0; j < 8; ++j) a[j] += co * v[j];
        }
#pragma unroll
        for (int j = 0; j < 8; ++j) a[j] *= dv;      // outer dinv[n]
        *(float4*)&r_lds[nl * 100 + c * 8] = make_float4(a[0], a[1], a[2], a[3]);
        *(float4*)&r_lds[nl * 100 + c * 8 + 4] = make_float4(a[4], a[5], a[6], a[7]);
    }

    // per-lane GRU weights (L2-resident; loaded while other waves still gather)
    int h = tid & 63;
    int w = tid >> 6;                     // wave 0..5
    float wz[FD], wh[FD];
#pragma unroll
    for (int f = 0; f < FD; ++f) {
        wz[f] = fused[f * 64 + h];
        wh[f] = fused[512 + f * 64 + h];
    }
    float bz = fused[1024 + h], bh = fused[1088 + h];
    __syncthreads();

    // ---- Phase N: GRU; wave w owns nodes [start, start+cnt) ----
    int start = w * 5 + (w < 2 ? w : 2);  // 0,6,12,17,22,27
    int cnt = (w < 2) ? 6 : 5;
    for (int k2 = 0; k2 < cnt; ++k2) {
        int nl0 = start + k2;
        const float* rp = &r_lds[nl0 * 100];
        float acc = 0.f;
#pragma unroll
        for (int t = 0; t < TD; ++t) {
            float4 a0 = *(const float4*)&rp[t * 8];
            float4 a1 = *(const float4*)&rp[t * 8 + 4];
            float z = bz, hh = bh;
            z += a0.x * wz[0] + a0.y * wz[1] + a0.z * wz[2] + a0.w * wz[3]
               + a1.x * wz[4] + a1.y * wz[5] + a1.z * wz[6] + a1.w * wz[7];
            hh += a0.x * wh[0] + a0.y * wh[1] + a0.z * wh[2] + a0.w * wh[3]
                + a1.x * wh[4] + a1.y * wh[5] + a1.z * wh[6] + a1.w * wh[7];
            float om = __builtin_amdgcn_rcpf(1.f + __expf(z));            // 1-sigmoid
            float Ht = 1.f - 2.f * __builtin_amdgcn_rcpf(1.f + __expf(2.f * hh));
            acc += probs_lds[t] * om * Ht;
        }
        rel_lds[nl0 * 68 + h] = fmaxf(acc, 0.f);
    }
    __syncthreads();

    // ---- Phase C: classifier, one (node,t) per thread ----
    {
        int nl2 = tid / 12, t = tid - nl2 * 12;
        int n2 = nbase + nl2;
        if (n2 < NN) {
            const float* rl = &rel_lds[nl2 * 68];
            const float* cwr = &cwT_lds[t * 68];
            float s = cb_lds[t];
#pragma unroll
            for (int k = 0; k < 16; ++k) {
                float4 rv = *(const float4*)&rl[k * 4];
                float4 cv = *(const float4*)&cwr[k * 4];
                s += rv.x * cv.x + rv.y * cv.y + rv.z * cv.z + rv.w * cv.w;
            }
            out[(size_t)n2 * TD + t] = s;
        }
    }
}

extern "C" void kernel_launch(void* const* d_in, const int* in_sizes, int n_in,
                              void* d_out, int out_size, void* d_ws, size_t ws_size,
                              hipStream_t stream) {
    const float* x         = (const float*)d_in[0];
    const int*   ei        = (const int*)d_in[1];
    const float* w         = (const float*)d_in[2];
    const float* conv_w    = (const float*)d_in[3];
    const float* conv_b    = (const float*)d_in[4];
    const float* lin_w     = (const float*)d_in[5];
    const float* lin_b     = (const float*)d_in[6];
    const float* attention = (const float*)d_in[7];
    const float* cls_w     = (const float*)d_in[8];
    const float* cls_b     = (const float*)d_in[9];
    float* ws  = (float*)d_ws;
    float* out = (float*)d_out;

    int*   ghist    = (int*)(ws + OFF_GHIST);
    int*   bktbase  = (int*)(ws + OFF_BASE);
    int*   cursor   = (int*)(ws + OFF_CUR);
    int*   rowstart = (int*)(ws + OFF_ROWST);
    float* dinv     = ws + OFF_DINV;
    float* fused    = ws + OFF_FUSED;
    uint4* xh4      = (uint4*)(ws + OFF_XH);
    int2*  bedge    = (int2*)(ws + OFF_BEDGE);

    k_precompute<<<1, 512, 0, stream>>>(conv_w, conv_b, lin_w, lin_b, attention,
                                        fused, ghist);
    k_xhalf<<<(NN * 12 + 255) / 256, 256, 0, stream>>>(x, xh4);
    k_hist<<<NT, 1024, 0, stream>>>(ei, ghist);
    k_scan<<<1, 512, 0, stream>>>(ghist, bktbase, cursor);
    k_place<<<NT, 1024, 0, stream>>>(ei, w, cursor, bedge);
    k_sort<<<NBUK, 512, 0, stream>>>(bktbase, bedge, rowstart, dinv);
    k_fused<<<(NN + 31) / 32, 384, 0, stream>>>(xh4, dinv, rowstart, bedge,
                                                fused, cls_w, cls_b, out);
}

// Round 15
// 158.157 us; speedup vs baseline: 1.0743x; 1.0743x over previous
//
#include <hip/hip_runtime.h>
#include <hip/hip_fp16.h>
#include <math.h>

#define NN 50000
#define FD 8
#define TD 12
#define HD 64
#define FT 96            // FD*TD halves per node
#define EE 1600000
#define NBUK 391         // ceil(NN/128) dst buckets of 128 nodes
#define TILE 16384
#define NT 98            // ceil(EE/TILE)
#define XB 586           // ceil(NN*12/1024) xhalf blocks
#define SORTCAP 5120     // LDS staging cap per bucket (mean 4096, sigma 64 -> +16s)

// ws offsets (4B units)
#define OFF_GHIST 0                      // int[NBUK]
#define OFF_BASE  512                    // int[NBUK+1]
#define OFF_CUR   1024                   // int[NBUK]
#define OFF_ROWST 2048                   // int[NN+1]
#define OFF_DINV  (2048 + NN + 16)       // float[NN]
#define OFF_FUSED (OFF_DINV + NN)        // float[1164]
#define OFF_THIST (OFF_FUSED + 1184)     // int[NT*NBUK] per-tile bucket counts
#define OFF_XH    (OFF_THIST + 38400)    // half[NN*FT] t-major = NN*48 units
#define OFF_BEDGE (OFF_XH + NN*48)       // int2[EE] = 2*EE units
#define OFF_AGGH  (OFF_BEDGE + 2*EE)     // half[NN*FT] t-major = NN*48 units
// total ~= 8.15M units ~= 32.6 MB

__device__ inline void h8f(uint4 h, float* f) {
    const __half2* p = (const __half2*)&h;
#pragma unroll
    for (int i = 0; i < 4; ++i) {
        float2 v = __half22float2(p[i]);
        f[2 * i] = v.x; f[2 * i + 1] = v.y;
    }
}

__device__ inline uint4 f8h(const float* f) {
    uint4 o;
    __half2* p = (__half2*)&o;
#pragma unroll
    for (int i = 0; i < 4; ++i) p[i] = __floats2half2_rn(f[2 * i], f[2 * i + 1]);
    return o;
}

// merged front-end: blocks [0,NT) = hist (+ per-tile counts), [NT,NT+XB) = x->fp16
// transpose, [NT+XB] = weight-fusion precompute. All inputs independent.
__global__ __launch_bounds__(1024) void k_front(const float* __restrict__ x,
                                                uint4* __restrict__ xh4,
                                                const int* __restrict__ ei,
                                                int* __restrict__ ghist,
                                                int* __restrict__ thist,
                                                const float* __restrict__ conv_w,
                                                const float* __restrict__ conv_b,
                                                const float* __restrict__ lin_w,
                                                const float* __restrict__ lin_b,
                                                const float* __restrict__ attention,
                                                float* __restrict__ fused) {
    int b = blockIdx.x;
    int tid = threadIdx.x;
    if (b < NT) {
        // ---- histogram tile ----
        __shared__ int h[NBUK];
        for (int i = tid; i < NBUK; i += 1024) h[i] = 0;
        __syncthreads();
        int base = b * TILE;
        for (int i = 0; i < TILE / 1024; ++i) {
            int e = base + i * 1024 + tid;
            if (e < EE) atomicAdd(&h[ei[EE + e] >> 7], 1);
        }
        __syncthreads();
        int* trow = thist + b * NBUK;
        for (int i = tid; i < NBUK; i += 1024) {
            int c = h[i];
            trow[i] = c;
            if (c) atomicAdd(&ghist[i], c);
        }
    } else if (b < NT + XB) {
        // ---- x (f-major fp32) -> xh (t-major fp16) ----
        unsigned i = (unsigned)(b - NT) * 1024u + tid;
        if (i < (unsigned)NN * 12u) {
            unsigned n = i / 12u, t = i - n * 12u;
            const float* xp = x + (size_t)n * FT + t;
            float f[8];
#pragma unroll
            for (int k = 0; k < 8; ++k) f[k] = xp[k * 12];
            xh4[i] = f8h(f);
        }
    } else {
        // ---- weight fusion ----
        for (int idx = tid; idx < 1024; idx += 1024) {
            int sel = idx >> 9;
            int f = (idx & 511) >> 6;
            int h = idx & 63;
            const float* cw = conv_w + f * 192 + (sel ? 128 : 0);
            const float* lw = lin_w + (sel ? 2 * 128 * 64 : 0) + h;
            float s = 0.f;
            for (int k = 0; k < 64; ++k) s += cw[k] * lw[k * 64];
            fused[idx] = s;
        }
        if (tid < 128) {
            int sel = tid >> 6;
            int h = tid & 63;
            const float* cb = conv_b + (sel ? 128 : 0);
            const float* lw = lin_w + (sel ? 2 * 128 * 64 : 0) + h;
            float s = lin_b[(sel ? 2 * 64 : 0) + h];
            for (int k = 0; k < 64; ++k) s += cb[k] * lw[k * 64];
            fused[1024 + tid] = s;
        }
        if (tid == 0) {
            float m = attention[0];
            for (int t = 1; t < TD; ++t) m = fmaxf(m, attention[t]);
            float e[TD], sum = 0.f;
            for (int t = 0; t < TD; ++t) { e[t] = __expf(attention[t] - m); sum += e[t]; }
            for (int t = 0; t < TD; ++t) fused[1152 + t] = e[t] / sum;
        }
    }
}

// exclusive scan of bucket counts -> bucket bases + append cursors
__global__ void k_scan(const int* __restrict__ ghist, int* __restrict__ bktbase,
                       int* __restrict__ cursor) {
    __shared__ int s[512];
    int tid = threadIdx.x;
    int v = (tid < NBUK) ? ghist[tid] : 0;
    s[tid] = v;
    __syncthreads();
    for (int off = 1; off < 512; off <<= 1) {
        int t = (tid >= off) ? s[tid - off] : 0;
        __syncthreads();
        s[tid] += t;
        __syncthreads();
    }
    int excl = s[tid] - v;
    if (tid < NBUK) { bktbase[tid] = excl; cursor[tid] = excl; }
    if (tid == NBUK - 1) bktbase[NBUK] = excl + v;   // == EE
}

// tile claims per-bucket ranges using the CACHED per-tile histogram (no re-scan
// of edges), then writes packed edges grouped by bucket: (src|dst_local<<16, w)
__global__ __launch_bounds__(1024) void k_place(const int* __restrict__ ei,
                                                const float* __restrict__ w,
                                                const int* __restrict__ thist,
                                                int* __restrict__ cursor,
                                                int2* __restrict__ bedge) {
    __shared__ int h[NBUK], bbase[NBUK];
    int tid = threadIdx.x;
    const int* tcnt = thist + blockIdx.x * NBUK;
    for (int i = tid; i < NBUK; i += 1024) {
        int c = tcnt[i];
        bbase[i] = c ? atomicAdd(&cursor[i], c) : 0;
        h[i] = 0;
    }
    __syncthreads();
    int base = blockIdx.x * TILE;
    for (int i = 0; i < TILE / 1024; ++i) {
        int e = base + i * 1024 + tid;
        if (e < EE) {
            int dst = ei[EE + e];
            int bk = dst >> 7;
            int rank = atomicAdd(&h[bk], 1);   // LDS rank within (tile,bucket)
            bedge[bbase[bk] + rank] =
                make_int2(ei[e] | ((dst & 127) << 16), __float_as_int(w[e]));
        }
    }
}

// per-bucket LDS counting sort by dst-local; writes back IN PLACE (block-local
// dense region), emits rowstart + dinv as by-products. Zero global atomics.
__global__ __launch_bounds__(512) void k_sort(const int* __restrict__ bktbase,
                                              int2* __restrict__ bedge,
                                              int* __restrict__ rowstart,
                                              float* __restrict__ dinv) {
    __shared__ int2 stage[SORTCAP];   // 40 KB
    __shared__ int cnt[128];
    __shared__ float wd[128];
    __shared__ int rowbase[128];
    int tid = threadIdx.x, b = blockIdx.x;
    int es = bktbase[b], ee = bktbase[b + 1];
    int count = ee - es;
    if (count > SORTCAP) count = SORTCAP;   // statistically unreachable
    if (tid < 128) { cnt[tid] = 0; wd[tid] = 0.f; }
    __syncthreads();
    for (int i = tid; i < count; i += 512) {
        int2 u = bedge[es + i];
        stage[i] = u;
        int dl = u.x >> 16;
        atomicAdd(&cnt[dl], 1);
        atomicAdd(&wd[dl], __int_as_float(u.y));
    }
    __syncthreads();
    if (tid < 128) rowbase[tid] = cnt[tid];
    __syncthreads();
    for (int off = 1; off < 128; off <<= 1) {
        int t = 0;
        if (tid >= off && tid < 128) t = rowbase[tid - off];
        __syncthreads();
        if (tid < 128) rowbase[tid] += t;
        __syncthreads();
    }
    int dbase = b << 7;
    if (tid < 128) {
        int excl = rowbase[tid] - cnt[tid];
        rowbase[tid] = excl;
        if (dbase + tid < NN) {
            rowstart[dbase + tid] = es + excl;
            dinv[dbase + tid] = rsqrtf(1.0f + wd[tid]);   // self-loop weight 1
        }
        cnt[tid] = 0;   // reuse as per-dst rank cursor
    }
    if (b == NBUK - 1 && tid == 0) rowstart[NN] = ee;
    __syncthreads();
    for (int i = tid; i < count; i += 512) {
        int2 u = stage[i];
        int dl = u.x >> 16;
        int pos = atomicAdd(&cnt[dl], 1);
        bedge[es + rowbase[dl] + pos] = make_int2(u.x & 0xFFFF, u.y);
    }
}

// thread = (node, uint4-chunk of 8 halves). 12 lanes/node, 16B/lane loads.
// Flat grid, no barriers. 4 independent edge chains for memory-level parallelism.
__global__ __launch_bounds__(256) void k_gather(const uint4* __restrict__ xh4,
                                                const float* __restrict__ dinv,
                                                const int* __restrict__ rowstart,
                                                const int2* __restrict__ edata,
                                                uint4* __restrict__ aggh) {
    unsigned t = blockIdx.x * 256u + threadIdx.x;
    if (t >= (unsigned)NN * 12u) return;
    unsigned n = t / 12u;
    unsigned c = t - n * 12u;
    float dv = dinv[n];
    float a[8];
    h8f(xh4[n * 12u + c], a);
#pragma unroll
    for (int j = 0; j < 8; ++j) a[j] *= dv;          // self-loop dinv[n]*x[n]
    int rs = rowstart[n], re = rowstart[n + 1];
    int k = rs;
    for (; k + 3 < re; k += 4) {                     // 4 independent chains
        int2 p0 = edata[k], p1 = edata[k + 1], p2 = edata[k + 2], p3 = edata[k + 3];
        float c0 = dinv[p0.x] * __int_as_float(p0.y);
        float c1 = dinv[p1.x] * __int_as_float(p1.y);
        float c2 = dinv[p2.x] * __int_as_float(p2.y);
        float c3 = dinv[p3.x] * __int_as_float(p3.y);
        float v0[8], v1[8], v2[8], v3[8];
        h8f(xh4[(unsigned)p0.x * 12u + c], v0);
        h8f(xh4[(unsigned)p1.x * 12u + c], v1);
        h8f(xh4[(unsigned)p2.x * 12u + c], v2);
        h8f(xh4[(unsigned)p3.x * 12u + c], v3);
#pragma unroll
        for (int j = 0; j < 8; ++j)
            a[j] += c0 * v0[j] + c1 * v1[j] + c2 * v2[j] + c3 * v3[j];
    }
    for (; k < re; ++k) {
        int2 p = edata[k];
        float co = dinv[p.x] * __int_as_float(p.y);
        float v[8];
        h8f(xh4[(unsigned)p.x * 12u + c], v);
#pragma unroll
        for (int j = 0; j < 8; ++j) a[j] += co * v[j];
    }
#pragma unroll
    for (int j = 0; j < 8; ++j) a[j] *= dv;          // outer dinv[n]
    aggh[n * 12u + c] = f8h(a);
}

// h-per-lane GRU: lane = h, weights in registers, b128 LDS reads, 2-node ILP,
// rcp-based gates (R13-proven).
__global__ __launch_bounds__(256) void k_node(const uint4* __restrict__ aggh,
                                              const float* __restrict__ fused,
                                              const float* __restrict__ cls_w,
                                              const float* __restrict__ cls_b,
                                              float* __restrict__ out) {
    __shared__ float r_lds[32 * 100];     // 32 nodes x 96 (t*8+f), stride 100
    __shared__ float rel_lds[32 * 68];    // [node][h], stride 68 (16B-aligned)
    __shared__ float cwT_lds[12 * 68];    // cw transposed [t][h], stride 68
    __shared__ float cb_lds[12];
    __shared__ float probs_lds[12];
    int tid = threadIdx.x;
    int nbase = blockIdx.x * 32;

    for (int id = tid; id < 384; id += 256) {
        int nl = id / 12, c = id - nl * 12;
        float f[8] = {0, 0, 0, 0, 0, 0, 0, 0};
        int n = nbase + nl;
        if (n < NN) h8f(aggh[(size_t)n * 12 + c], f);
        *(float4*)&r_lds[nl * 100 + c * 8] = make_float4(f[0], f[1], f[2], f[3]);
        *(float4*)&r_lds[nl * 100 + c * 8 + 4] = make_float4(f[4], f[5], f[6], f[7]);
    }
    for (int id = tid; id < 768; id += 256) {
        int hh = id / 12, t = id - hh * 12;
        cwT_lds[t * 68 + hh] = cls_w[id];
    }
    if (tid < 12) { cb_lds[tid] = cls_b[tid]; probs_lds[tid] = fused[1152 + tid]; }

    int h = tid & 63;
    int w = tid >> 6;
    float wz[FD], wh[FD];
#pragma unroll
    for (int f = 0; f < FD; ++f) {
        wz[f] = fused[f * 64 + h];
        wh[f] = fused[512 + f * 64 + h];
    }
    float bz = fused[1024 + h], bh = fused[1088 + h];
    __syncthreads();

#pragma unroll
    for (int np = 0; np < 4; ++np) {
        int nl0 = w * 8 + np * 2;
        const float* rp0 = &r_lds[nl0 * 100];
        const float* rp1 = rp0 + 100;
        float acc0 = 0.f, acc1 = 0.f;
#pragma unroll
        for (int t = 0; t < TD; ++t) {
            float4 a0 = *(const float4*)&rp0[t * 8];
            float4 a1 = *(const float4*)&rp0[t * 8 + 4];
            float4 b0 = *(const float4*)&rp1[t * 8];
            float4 b1 = *(const float4*)&rp1[t * 8 + 4];
            float z0 = bz, h0 = bh, z1 = bz, h1 = bh;
            z0 += a0.x * wz[0] + a0.y * wz[1] + a0.z * wz[2] + a0.w * wz[3]
                + a1.x * wz[4] + a1.y * wz[5] + a1.z * wz[6] + a1.w * wz[7];
            h0 += a0.x * wh[0] + a0.y * wh[1] + a0.z * wh[2] + a0.w * wh[3]
                + a1.x * wh[4] + a1.y * wh[5] + a1.z * wh[6] + a1.w * wh[7];
            z1 += b0.x * wz[0] + b0.y * wz[1] + b0.z * wz[2] + b0.w * wz[3]
                + b1.x * wz[4] + b1.y * wz[5] + b1.z * wz[6] + b1.w * wz[7];
            h1 += b0.x * wh[0] + b0.y * wh[1] + b0.z * wh[2] + b0.w * wh[3]
                + b1.x * wh[4] + b1.y * wh[5] + b1.z * wh[6] + b1.w * wh[7];
            float om0 = __builtin_amdgcn_rcpf(1.f + __expf(z0));
            float om1 = __builtin_amdgcn_rcpf(1.f + __expf(z1));
            float Ht0 = 1.f - 2.f * __builtin_amdgcn_rcpf(1.f + __expf(2.f * h0));
            float Ht1 = 1.f - 2.f * __builtin_amdgcn_rcpf(1.f + __expf(2.f * h1));
            float p = probs_lds[t];
            acc0 += p * om0 * Ht0;
            acc1 += p * om1 * Ht1;
        }
        rel_lds[nl0 * 68 + h] = fmaxf(acc0, 0.f);
        rel_lds[(nl0 + 1) * 68 + h] = fmaxf(acc1, 0.f);
    }
    __syncthreads();

    for (int id = tid; id < 384; id += 256) {
        int nl = id / 12, t = id - nl * 12;
        int n = nbase + nl;
        if (n >= NN) continue;
        const float* rl = &rel_lds[nl * 68];
        const float* cwr = &cwT_lds[t * 68];
        float s = cb_lds[t];
#pragma unroll
        for (int k = 0; k < 16; ++k) {
            float4 rv = *(const float4*)&rl[k * 4];
            float4 cv = *(const float4*)&cwr[k * 4];
            s += rv.x * cv.x + rv.y * cv.y + rv.z * cv.z + rv.w * cv.w;
        }
        out[(size_t)n * TD + t] = s;
    }
}

extern "C" void kernel_launch(void* const* d_in, const int* in_sizes, int n_in,
                              void* d_out, int out_size, void* d_ws, size_t ws_size,
                              hipStream_t stream) {
    const float* x         = (const float*)d_in[0];
    const int*   ei        = (const int*)d_in[1];
    const float* w         = (const float*)d_in[2];
    const float* conv_w    = (const float*)d_in[3];
    const float* conv_b    = (const float*)d_in[4];
    const float* lin_w     = (const float*)d_in[5];
    const float* lin_b     = (const float*)d_in[6];
    const float* attention = (const float*)d_in[7];
    const float* cls_w     = (const float*)d_in[8];
    const float* cls_b     = (const float*)d_in[9];
    float* ws  = (float*)d_ws;
    float* out = (float*)d_out;

    int*   ghist    = (int*)(ws + OFF_GHIST);
    int*   bktbase  = (int*)(ws + OFF_BASE);
    int*   cursor   = (int*)(ws + OFF_CUR);
    int*   rowstart = (int*)(ws + OFF_ROWST);
    float* dinv     = ws + OFF_DINV;
    float* fused    = ws + OFF_FUSED;
    int*   thist    = (int*)(ws + OFF_THIST);
    uint4* xh4      = (uint4*)(ws + OFF_XH);
    int2*  bedge    = (int2*)(ws + OFF_BEDGE);
    uint4* aggh     = (uint4*)(ws + OFF_AGGH);

    hipMemsetAsync(ghist, 0, NBUK * sizeof(int), stream);
    k_front<<<NT + XB + 1, 1024, 0, stream>>>(x, xh4, ei, ghist, thist,
                                              conv_w, conv_b, lin_w, lin_b,
                                              attention, fused);
    k_scan<<<1, 512, 0, stream>>>(ghist, bktbase, cursor);
    k_place<<<NT, 1024, 0, stream>>>(ei, w, thist, cursor, bedge);
    k_sort<<<NBUK, 512, 0, stream>>>(bktbase, bedge, rowstart, dinv);
    {
        unsigned total = (unsigned)NN * 12u;   // 600K threads
        k_gather<<<(total + 255) / 256, 256, 0, stream>>>(xh4, dinv,
                                                          rowstart, bedge, aggh);
    }
    k_node<<<(NN + 31) / 32, 256, 0, stream>>>(aggh, fused, cls_w, cls_b, out);
}